// Round 19
// baseline (628.317 us; speedup 1.0000x reference)
//
#include <hip/hip_runtime.h>
#include <stdint.h>

// TopKRouter: T=32768, D=1024, E=64, k=2 (device scalar), C=1280 (from out_size).
//
// Correctness model (rounds 0-18 ledger): np golden = numpy f32 transliteration.
// logits = x @ W.T + b, OpenBLAS sgemm, K panels [0,512)[512,1024) (512/512):
//   single-accumulator ascending-k f32 FMA chain per panel, panels summed
//   left-to-right, + b (f32).  [512/512 fixed cells A,B,C: 26160/27872/30192]
// softmax f32, numpy semantics from actual numpy source:
//   exp = AVX512 FLOAT_exp: Cephes constants WITH FMA, rint quadrant, scalef
//         [fixed cell D: r18 17056 -> 3456]
//   sum = FLOAT_pairwise_sum at baseline SIMD (SSE3 npyv, 4 lanes), n=64:
//         R_j[l]=e[4j+l]+e[32+4j+l]; tree ((R0+R1)+(R2+R3))+((R4+R5)+(R6+R7));
//         horizontal = SSE3 HADD: S=(s0+s1)+(s2+s3)   [r19 change: was movehl]
//   p = e/S (CR f32 divide), max-subtract exact.
// top-k & capacity sort on f32 probs, ties -> lower index (stable).
// expert_indices stored as f32 values (-1.0f padding).

#define THREADS 256
#define KMAX 16

// ---- numpy AVX512 FLOAT_exp replica: Cephes constants, FMA, rint quadrant ---
__device__ __forceinline__ float np_expf_avx512(float x)
{
    const float log2e = 1.442695040888963f;      // NPY_LOG2Ef
    float t = x * log2e;                          // separate mul (vmulps)
    float q = rintf(t);                           // roundscale nearest-even
    float r = fmaf(q, -0.693359375f, x);          // Cody-Waite hi (fma)
    r = fmaf(q, 2.12194440e-4f, r);               // Cody-Waite lo (fma)
    float y = 1.9875691500E-4f;                   // cephes_exp_p0..p5
    y = fmaf(y, r, 1.3981999507E-3f);
    y = fmaf(y, r, 8.3334519073E-3f);
    y = fmaf(y, r, 4.1665795894E-2f);
    y = fmaf(y, r, 1.6666665459E-1f);
    y = fmaf(y, r, 5.0000001201E-1f);
    float rr = r * r;                             // separate mul
    y = fmaf(y, rr, r);                           // poly*r^2 + r
    y = y + 1.0f;
    return ldexpf(y, (int)q);                     // vscalefps (q integral)
}

// ---------------- Kernel T: transpose W (E x D) -> WT (D x E, k-major) -------
__global__ __launch_bounds__(256)
void transpose_w_kernel(const float* __restrict__ W, float* __restrict__ WT,
                        int D, int E)
{
    const int e = blockIdx.x;
    for (int k = threadIdx.x; k < D; k += 256)
        WT[(size_t)k * E + e] = W[(size_t)e * D + k];
}

// ---------------- Kernel A: f32 logits, 512/512 K-panel FMA chains -----------
// Grid: T/64 blocks x 128 thr (2 waves). lane = token (64/block);
// wave w handles experts [32w, 32w+32). Per thread: acc[32] f32 chains.
// x staged transposed in LDS (stride 65, conflict-free).
#define KC 64
__global__ __launch_bounds__(128)
void gemm_f32_kernel(const float* __restrict__ x, const float* __restrict__ WT,
                     const float* __restrict__ bias,
                     float* __restrict__ logits_out, int T, int D, int E)
{
    const int tid  = threadIdx.x;
    const int lane = tid & 63;
    const int w    = tid >> 6;            // 0..1: expert half
    const int tok0 = blockIdx.x * 64;

    __shared__ float XT[64 * 65];         // XT[k][t] stride 65; reused as LT

    float acc[32], ztot[32];
#pragma unroll
    for (int j = 0; j < 32; ++j) { acc[j] = 0.0f; ztot[j] = 0.0f; }

    const int cc = tid & 15;              // float4 index within a 64-float row
    const int r0 = tid >> 4;              // 0..7

    for (int kc = 0; kc < 1024; kc += KC) {
        __syncthreads();
        // stage XT[k][t] = x[tok0+t][kc+k]
        for (int r = r0; r < 64; r += 8) {
            float4 v = *reinterpret_cast<const float4*>(
                x + (size_t)(tok0 + r) * D + kc + 4 * cc);
            XT[(4 * cc + 0) * 65 + r] = v.x;
            XT[(4 * cc + 1) * 65 + r] = v.y;
            XT[(4 * cc + 2) * 65 + r] = v.z;
            XT[(4 * cc + 3) * 65 + r] = v.w;
        }
        __syncthreads();

        for (int k = 0; k < KC; ++k) {
            float xv = XT[k * 65 + lane];
            const float4* wq = reinterpret_cast<const float4*>(
                WT + (size_t)(kc + k) * 64 + w * 32);
#pragma unroll
            for (int eq = 0; eq < 8; ++eq) {
                float4 wv = wq[eq];
                acc[4 * eq + 0] = fmaf(xv, wv.x, acc[4 * eq + 0]);
                acc[4 * eq + 1] = fmaf(xv, wv.y, acc[4 * eq + 1]);
                acc[4 * eq + 2] = fmaf(xv, wv.z, acc[4 * eq + 2]);
                acc[4 * eq + 3] = fmaf(xv, wv.w, acc[4 * eq + 3]);
            }
            int kg = kc + k + 1;
            // K panels 512/512
            if (kg == 512 || kg == 1024) {
#pragma unroll
                for (int j = 0; j < 32; ++j) { ztot[j] += acc[j]; acc[j] = 0.0f; }
            }
        }
    }

#pragma unroll
    for (int j = 0; j < 32; ++j) ztot[j] += bias[w * 32 + j];

    // transpose via LDS (reuse XT as LT[t][e], stride 65), coalesced store
    __syncthreads();
#pragma unroll
    for (int j = 0; j < 32; ++j) XT[lane * 65 + w * 32 + j] = ztot[j];
    __syncthreads();
    for (int it = 0; it < 32; ++it) {
        int i = it * 128 + tid;           // 0..4095
        int t = i >> 6, e = i & 63;
        logits_out[(size_t)(tok0 + t) * 64 + e] = XT[t * 65 + e];
    }
}

// ------- Kernel B: numpy f32 softmax (AVX512 exp + SSE3 pairwise sum) --------
__global__ __launch_bounds__(THREADS)
void softmax_topk_kernel(const float* __restrict__ logits,
                         float* __restrict__ probs_out,
                         float* __restrict__ pf, int* __restrict__ eid,
                         const int* __restrict__ kptr, int T, int E)
{
    const int lane = threadIdx.x & 63;
    const int wid = threadIdx.x >> 6;
    int token = blockIdx.x * 4 + wid;
    if (token >= T) token = T - 1;

    int k = *kptr;
    if (k > E) k = E;
    if (k > KMAX) k = KMAX;

    float z = logits[(size_t)token * 64 + lane];

    float m = z;
#pragma unroll
    for (int d = 1; d < 64; d <<= 1) m = fmaxf(m, __shfl_xor(m, d));

    float e32 = np_expf_avx512(z - m);

    __shared__ float sh[4][64];
    sh[wid][lane] = e32;
    __syncthreads();

    // numpy FLOAT_pairwise_sum, baseline npyv (SSE, 4 lanes), n=64:
    // R_j[l] = e[4j+l] + e[32+4j+l]; lanewise tree; SSE3 hadd horizontal.
    const float* row = sh[wid];
    float s[4];
#pragma unroll
    for (int l = 0; l < 4; ++l) {
        float R0 = row[ 0 + l] + row[32 + l];
        float R1 = row[ 4 + l] + row[36 + l];
        float R2 = row[ 8 + l] + row[40 + l];
        float R3 = row[12 + l] + row[44 + l];
        float R4 = row[16 + l] + row[48 + l];
        float R5 = row[20 + l] + row[52 + l];
        float R6 = row[24 + l] + row[56 + l];
        float R7 = row[28 + l] + row[60 + l];
        s[l] = ((R0 + R1) + (R2 + R3)) + ((R4 + R5) + (R6 + R7));
    }
    float S = (s[0] + s[1]) + (s[2] + s[3]);   // SSE3 hadd horizontal order

    float p = e32 / S;                    // CR f32 divide
    probs_out[(size_t)token * 64 + lane] = p;

    // per-token top-k on f32 p, tie -> lower expert id
    float pv = p;
    for (int j = 0; j < k; ++j) {
        float bp = pv;
        int be = lane;
#pragma unroll
        for (int d = 1; d < 64; d <<= 1) {
            float op = __shfl_xor(bp, d);
            int oe = __shfl_xor(be, d);
            if (op > bp || (op == bp && oe < be)) { bp = op; be = oe; }
        }
        if (lane == 0) {
            int slot = token * k + j;
            pf[slot] = bp;
            eid[slot] = be;
        }
        if (lane == be) pv = -1.0f;
    }
}

// ---------------- Kernel C: per-expert gather + bitonic sort ----------------
// Key = (f32 prob bits << 32) | (0xFFFFFFFF - slot); descending u64 sort
// == prob desc, tie -> lower slot.
#define MAXN 4096
__global__ __launch_bounds__(THREADS)
void expert_sort_kernel(const float* __restrict__ pf, const int* __restrict__ eid,
                        const int* __restrict__ kptr,
                        float* __restrict__ out_probs, float* __restrict__ out_idx,
                        int T, int E, int C)
{
    __shared__ unsigned long long keys[MAXN];
    __shared__ int cnt;
    const int e = blockIdx.x;
    const int tid = threadIdx.x;
    if (tid == 0) cnt = 0;
    __syncthreads();

    int k = *kptr;
    if (k > E) k = E;
    if (k > KMAX) k = KMAX;
    const int nslots = T * k;

    for (int s = tid; s < nslots; s += THREADS) {
        if (eid[s] == e) {
            int pos = atomicAdd(&cnt, 1);
            if (pos < MAXN) {
                unsigned pbits = __float_as_uint(pf[s]);
                keys[pos] = ((unsigned long long)pbits << 32)
                          | (unsigned long long)(0xFFFFFFFFu - (unsigned)s);
            }
        }
    }
    __syncthreads();

    int n = cnt;
    if (n > MAXN) n = MAXN;

    int P = 1;
    while (P < n) P <<= 1;
    for (int i = n + tid; i < P; i += THREADS) keys[i] = 0ULL;
    __syncthreads();

    for (int size = 2; size <= P; size <<= 1) {
        for (int stride = size >> 1; stride > 0; stride >>= 1) {
            for (int i = tid; i < P; i += THREADS) {
                int j = i ^ stride;
                if (j > i) {
                    unsigned long long a = keys[i], bkey = keys[j];
                    bool up = ((i & size) == 0);
                    bool doswap = up ? (a < bkey) : (a > bkey);
                    if (doswap) { keys[i] = bkey; keys[j] = a; }
                }
            }
            __syncthreads();
        }
    }

    for (int c = tid; c < C; c += THREADS) {
        float prob, idxv;
        if (c < n) {
            unsigned long long kk = keys[c];
            prob = __uint_as_float((unsigned)(kk >> 32));
            unsigned slot = 0xFFFFFFFFu - (unsigned)(kk & 0xFFFFFFFFull);
            idxv = (float)(slot / (unsigned)k);
        } else {
            prob = 0.0f;
            idxv = -1.0f;
        }
        out_probs[(size_t)e * C + c] = prob;
        out_idx[(size_t)e * C + c] = idxv;
    }
}

extern "C" void kernel_launch(void* const* d_in, const int* in_sizes, int n_in,
                              void* d_out, int out_size, void* d_ws, size_t ws_size,
                              hipStream_t stream)
{
    const float* x   = (const float*)d_in[0];
    const float* W   = (const float*)d_in[1];
    const float* b   = (const float*)d_in[2];
    const int* kptr  = (const int*)d_in[3];

    const int E = in_sizes[2];            // 64
    const int D = in_sizes[1] / E;        // 1024
    const int T = in_sizes[0] / D;        // 32768
    const int C = (out_size - 2 * T * E) / (2 * E);   // 1280

    float* out_logits = (float*)d_out;
    float* out_probs  = out_logits + (size_t)T * E;
    float* out_eprobs = out_probs  + (size_t)T * E;
    float* out_eidx   = out_eprobs + (size_t)E * C;

    // workspace: WT (D*E f32) | pf (T*KMAX f32) | eid (T*KMAX i32)
    float* WT  = (float*)d_ws;
    float* pf  = (float*)((char*)d_ws + (size_t)D * E * sizeof(float));
    int*   eid = (int*)((char*)pf + (size_t)T * KMAX * sizeof(float));

    transpose_w_kernel<<<E, 256, 0, stream>>>(W, WT, D, E);
    gemm_f32_kernel<<<T / 64, 128, 0, stream>>>(
        x, WT, b, out_logits, T, D, E);
    softmax_topk_kernel<<<(T + 3) / 4, THREADS, 0, stream>>>(
        out_logits, out_probs, pf, eid, kptr, T, E);
    expert_sort_kernel<<<E, THREADS, 0, stream>>>(
        pf, eid, kptr, out_eprobs, out_eidx, T, E, C);
}

// Round 20
// 432.726 us; speedup vs baseline: 1.4520x; 1.4520x over previous
//
#include <hip/hip_runtime.h>
#include <stdint.h>

// TopKRouter: T=32768, D=1024, E=64, k=2 (device scalar), C=1280 (from out_size).
//
// Correctness model (VERIFIED PASSING r19): np golden = numpy f32 transliteration.
// logits = x @ W.T + b, K panels [0,512)[512,1024) (512/512): single-accumulator
//   ascending-k f32 FMA chain per panel, panels summed left-to-right, + b (f32).
// softmax f32: AVX512 FLOAT_exp (Cephes constants, FMA, rint, scalef);
//   pairwise sum = SSE npyv 4-lane: R_j[l]=e[4j+l]+e[32+4j+l], lanewise tree,
//   SSE3 hadd horizontal S=(s0+s1)+(s2+s3); CR f32 divide; exact max-subtract.
// top-k & capacity sort on f32 probs, ties -> lower index (stable).
// expert_indices stored as f32 values (-1.0f padding).
//
// r20 perf change (bit-exact preserving): GEMM remapped 128thr/acc[32] ->
// 512thr/acc[8] (8 waves, wave w = experts [8w,8w+8)). Same per-element FMA
// chain order; 4x occupancy (1->4 waves/SIMD), shorter per-thread chain,
// VGPR headroom for load prefetch. [r19 counters: VALUBusy 6.9%, Occ 12%,
// 484us vs 27us FMA floor -> latency-bound, grid-starved]

#define THREADS 256
#define KMAX 16

// ---- numpy AVX512 FLOAT_exp replica: Cephes constants, FMA, rint quadrant ---
__device__ __forceinline__ float np_expf_avx512(float x)
{
    const float log2e = 1.442695040888963f;      // NPY_LOG2Ef
    float t = x * log2e;                          // separate mul (vmulps)
    float q = rintf(t);                           // roundscale nearest-even
    float r = fmaf(q, -0.693359375f, x);          // Cody-Waite hi (fma)
    r = fmaf(q, 2.12194440e-4f, r);               // Cody-Waite lo (fma)
    float y = 1.9875691500E-4f;                   // cephes_exp_p0..p5
    y = fmaf(y, r, 1.3981999507E-3f);
    y = fmaf(y, r, 8.3334519073E-3f);
    y = fmaf(y, r, 4.1665795894E-2f);
    y = fmaf(y, r, 1.6666665459E-1f);
    y = fmaf(y, r, 5.0000001201E-1f);
    float rr = r * r;                             // separate mul
    y = fmaf(y, rr, r);                           // poly*r^2 + r
    y = y + 1.0f;
    return ldexpf(y, (int)q);                     // vscalefps (q integral)
}

// ---------------- Kernel T: transpose W (E x D) -> WT (D x E, k-major) -------
__global__ __launch_bounds__(256)
void transpose_w_kernel(const float* __restrict__ W, float* __restrict__ WT,
                        int D, int E)
{
    const int e = blockIdx.x;
    for (int k = threadIdx.x; k < D; k += 256)
        WT[(size_t)k * E + e] = W[(size_t)e * D + k];
}

// ---------------- Kernel A: f32 logits, 512/512 K-panel FMA chains -----------
// Grid: T/64 blocks x 512 thr (8 waves). lane = token (64/block);
// wave w handles experts [8w, 8w+8). Per thread: acc[8] f32 chains.
// x staged transposed in LDS (stride 65, conflict-free).
#define KC 64
__global__ __launch_bounds__(512)
void gemm_f32_kernel(const float* __restrict__ x, const float* __restrict__ WT,
                     const float* __restrict__ bias,
                     float* __restrict__ logits_out, int T, int D, int E)
{
    const int tid  = threadIdx.x;
    const int lane = tid & 63;
    const int w    = tid >> 6;            // 0..7: expert octet
    const int tok0 = blockIdx.x * 64;

    __shared__ float XT[64 * 65];         // XT[k][t] stride 65; reused as LT

    float acc[8], ztot[8];
#pragma unroll
    for (int j = 0; j < 8; ++j) { acc[j] = 0.0f; ztot[j] = 0.0f; }

    const int cc = tid & 15;              // float4 index within a 64-float row
    const int r0 = tid >> 4;              // 0..31

    for (int kc = 0; kc < 1024; kc += KC) {
        __syncthreads();
        // stage XT[k][t] = x[tok0+t][kc+k]   (512 threads, 2 rows each)
        for (int r = r0; r < 64; r += 32) {
            float4 v = *reinterpret_cast<const float4*>(
                x + (size_t)(tok0 + r) * D + kc + 4 * cc);
            XT[(4 * cc + 0) * 65 + r] = v.x;
            XT[(4 * cc + 1) * 65 + r] = v.y;
            XT[(4 * cc + 2) * 65 + r] = v.z;
            XT[(4 * cc + 3) * 65 + r] = v.w;
        }
        __syncthreads();

#pragma unroll 8
        for (int k = 0; k < KC; ++k) {
            float xv = XT[k * 65 + lane];
            const float4* wq = reinterpret_cast<const float4*>(
                WT + (size_t)(kc + k) * 64 + w * 8);
            float4 wv0 = wq[0];
            float4 wv1 = wq[1];
            acc[0] = fmaf(xv, wv0.x, acc[0]);
            acc[1] = fmaf(xv, wv0.y, acc[1]);
            acc[2] = fmaf(xv, wv0.z, acc[2]);
            acc[3] = fmaf(xv, wv0.w, acc[3]);
            acc[4] = fmaf(xv, wv1.x, acc[4]);
            acc[5] = fmaf(xv, wv1.y, acc[5]);
            acc[6] = fmaf(xv, wv1.z, acc[6]);
            acc[7] = fmaf(xv, wv1.w, acc[7]);
        }
        // K panels 512/512: fold at tile boundaries only (bit-exact)
        int kend = kc + KC;
        if (kend == 512 || kend == 1024) {
#pragma unroll
            for (int j = 0; j < 8; ++j) { ztot[j] += acc[j]; acc[j] = 0.0f; }
        }
    }

#pragma unroll
    for (int j = 0; j < 8; ++j) ztot[j] += bias[w * 8 + j];

    // transpose via LDS (reuse XT as LT[t][e], stride 65), coalesced store
    __syncthreads();
#pragma unroll
    for (int j = 0; j < 8; ++j) XT[lane * 65 + w * 8 + j] = ztot[j];
    __syncthreads();
    for (int it = 0; it < 8; ++it) {
        int i = it * 512 + tid;           // 0..4095
        int t = i >> 6, e = i & 63;
        logits_out[(size_t)(tok0 + t) * 64 + e] = XT[t * 65 + e];
    }
}

// ------- Kernel B: numpy f32 softmax (AVX512 exp + SSE3 pairwise sum) --------
__global__ __launch_bounds__(THREADS)
void softmax_topk_kernel(const float* __restrict__ logits,
                         float* __restrict__ probs_out,
                         float* __restrict__ pf, int* __restrict__ eid,
                         const int* __restrict__ kptr, int T, int E)
{
    const int lane = threadIdx.x & 63;
    const int wid = threadIdx.x >> 6;
    int token = blockIdx.x * 4 + wid;
    if (token >= T) token = T - 1;

    int k = *kptr;
    if (k > E) k = E;
    if (k > KMAX) k = KMAX;

    float z = logits[(size_t)token * 64 + lane];

    float m = z;
#pragma unroll
    for (int d = 1; d < 64; d <<= 1) m = fmaxf(m, __shfl_xor(m, d));

    float e32 = np_expf_avx512(z - m);

    __shared__ float sh[4][64];
    sh[wid][lane] = e32;
    __syncthreads();

    // numpy FLOAT_pairwise_sum, baseline npyv (SSE, 4 lanes), n=64:
    // R_j[l] = e[4j+l] + e[32+4j+l]; lanewise tree; SSE3 hadd horizontal.
    const float* row = sh[wid];
    float s[4];
#pragma unroll
    for (int l = 0; l < 4; ++l) {
        float R0 = row[ 0 + l] + row[32 + l];
        float R1 = row[ 4 + l] + row[36 + l];
        float R2 = row[ 8 + l] + row[40 + l];
        float R3 = row[12 + l] + row[44 + l];
        float R4 = row[16 + l] + row[48 + l];
        float R5 = row[20 + l] + row[52 + l];
        float R6 = row[24 + l] + row[56 + l];
        float R7 = row[28 + l] + row[60 + l];
        s[l] = ((R0 + R1) + (R2 + R3)) + ((R4 + R5) + (R6 + R7));
    }
    float S = (s[0] + s[1]) + (s[2] + s[3]);   // SSE3 hadd horizontal order

    float p = e32 / S;                    // CR f32 divide
    probs_out[(size_t)token * 64 + lane] = p;

    // per-token top-k on f32 p, tie -> lower expert id
    float pv = p;
    for (int j = 0; j < k; ++j) {
        float bp = pv;
        int be = lane;
#pragma unroll
        for (int d = 1; d < 64; d <<= 1) {
            float op = __shfl_xor(bp, d);
            int oe = __shfl_xor(be, d);
            if (op > bp || (op == bp && oe < be)) { bp = op; be = oe; }
        }
        if (lane == 0) {
            int slot = token * k + j;
            pf[slot] = bp;
            eid[slot] = be;
        }
        if (lane == be) pv = -1.0f;
    }
}

// ---------------- Kernel C: per-expert gather + bitonic sort ----------------
// Key = (f32 prob bits << 32) | (0xFFFFFFFF - slot); descending u64 sort
// == prob desc, tie -> lower slot.
#define MAXN 4096
__global__ __launch_bounds__(THREADS)
void expert_sort_kernel(const float* __restrict__ pf, const int* __restrict__ eid,
                        const int* __restrict__ kptr,
                        float* __restrict__ out_probs, float* __restrict__ out_idx,
                        int T, int E, int C)
{
    __shared__ unsigned long long keys[MAXN];
    __shared__ int cnt;
    const int e = blockIdx.x;
    const int tid = threadIdx.x;
    if (tid == 0) cnt = 0;
    __syncthreads();

    int k = *kptr;
    if (k > E) k = E;
    if (k > KMAX) k = KMAX;
    const int nslots = T * k;

    for (int s = tid; s < nslots; s += THREADS) {
        if (eid[s] == e) {
            int pos = atomicAdd(&cnt, 1);
            if (pos < MAXN) {
                unsigned pbits = __float_as_uint(pf[s]);
                keys[pos] = ((unsigned long long)pbits << 32)
                          | (unsigned long long)(0xFFFFFFFFu - (unsigned)s);
            }
        }
    }
    __syncthreads();

    int n = cnt;
    if (n > MAXN) n = MAXN;

    int P = 1;
    while (P < n) P <<= 1;
    for (int i = n + tid; i < P; i += THREADS) keys[i] = 0ULL;
    __syncthreads();

    for (int size = 2; size <= P; size <<= 1) {
        for (int stride = size >> 1; stride > 0; stride >>= 1) {
            for (int i = tid; i < P; i += THREADS) {
                int j = i ^ stride;
                if (j > i) {
                    unsigned long long a = keys[i], bkey = keys[j];
                    bool up = ((i & size) == 0);
                    bool doswap = up ? (a < bkey) : (a > bkey);
                    if (doswap) { keys[i] = bkey; keys[j] = a; }
                }
            }
            __syncthreads();
        }
    }

    for (int c = tid; c < C; c += THREADS) {
        float prob, idxv;
        if (c < n) {
            unsigned long long kk = keys[c];
            prob = __uint_as_float((unsigned)(kk >> 32));
            unsigned slot = 0xFFFFFFFFu - (unsigned)(kk & 0xFFFFFFFFull);
            idxv = (float)(slot / (unsigned)k);
        } else {
            prob = 0.0f;
            idxv = -1.0f;
        }
        out_probs[(size_t)e * C + c] = prob;
        out_idx[(size_t)e * C + c] = idxv;
    }
}

extern "C" void kernel_launch(void* const* d_in, const int* in_sizes, int n_in,
                              void* d_out, int out_size, void* d_ws, size_t ws_size,
                              hipStream_t stream)
{
    const float* x   = (const float*)d_in[0];
    const float* W   = (const float*)d_in[1];
    const float* b   = (const float*)d_in[2];
    const int* kptr  = (const int*)d_in[3];

    const int E = in_sizes[2];            // 64
    const int D = in_sizes[1] / E;        // 1024
    const int T = in_sizes[0] / D;        // 32768
    const int C = (out_size - 2 * T * E) / (2 * E);   // 1280

    float* out_logits = (float*)d_out;
    float* out_probs  = out_logits + (size_t)T * E;
    float* out_eprobs = out_probs  + (size_t)T * E;
    float* out_eidx   = out_eprobs + (size_t)E * C;

    // workspace: WT (D*E f32) | pf (T*KMAX f32) | eid (T*KMAX i32)
    float* WT  = (float*)d_ws;
    float* pf  = (float*)((char*)d_ws + (size_t)D * E * sizeof(float));
    int*   eid = (int*)((char*)pf + (size_t)T * KMAX * sizeof(float));

    transpose_w_kernel<<<E, 256, 0, stream>>>(W, WT, D, E);
    gemm_f32_kernel<<<T / 64, 512, 0, stream>>>(
        x, WT, b, out_logits, T, D, E);
    softmax_topk_kernel<<<(T + 3) / 4, THREADS, 0, stream>>>(
        out_logits, out_probs, pf, eid, kptr, T, E);
    expert_sort_kernel<<<E, THREADS, 0, stream>>>(
        pf, eid, kptr, out_eprobs, out_eidx, T, E, C);
}